// Round 8
// baseline (731.986 us; speedup 1.0000x reference)
//
#include <hip/hip_runtime.h>
#include <hip/hip_bf16.h>

// r4: 407 (k_attn 185, 3 blk/CU, conflicts 1.1e7). r6: direct-global = request wall.
// r7: 427 (k_attn 233) — DMA dbuf degenerates: compiler drains vmcnt before ds_read
// (can't prove buffer disjointness) AND 64KB LDS -> 2 blk/CU kills cross-block overlap.
// r8: single-buffer KV (40KB -> 4 blk/CU, launch_bounds(256,4)); m97-style 2-barrier
// chunk loop; overlap comes from 4 independent blocks per CU, not intra-wave async.
// Swizzled LDS (0 conflicts) + XCD-affinity grid (FETCH 49MB) retained.

typedef unsigned short u16;
typedef unsigned int   u32;
typedef __attribute__((ext_vector_type(4))) float          floatx4;
typedef __attribute__((ext_vector_type(8))) short          shortx8;

#define EMB   768
#define SEQ   2048
#define NHEAD 12
#define HDIM  64
#define RPM   4096   // rows per modal (B*N)
#define NROW  8192   // total rows (2 modals)
#define NUNIT 48     // modal*B*H units

__device__ __forceinline__ float bf2f(u16 h) {
  union { u32 u; float f; } v; v.u = ((u32)h) << 16; return v.f;
}
__device__ __forceinline__ u16 f2bf(float f) {            // RNE
  union { float f; u32 u; } v; v.f = f;
  u32 r = v.u + 0x7fffu + ((v.u >> 16) & 1u);
  return (u16)(r >> 16);
}
__device__ __forceinline__ u16 f2bf_tr(float f) {         // truncate (P in [0,1])
  union { float f; u32 u; } v; v.f = f;
  return (u16)(v.u >> 16);
}
__device__ __forceinline__ float swz_max16(float v) {     // max over 16-lane group
  union { float f; int i; } a;
  a.f = v; a.i = __builtin_amdgcn_ds_swizzle(a.i, 0x041F); v = fmaxf(v, a.f);
  a.f = v; a.i = __builtin_amdgcn_ds_swizzle(a.i, 0x081F); v = fmaxf(v, a.f);
  a.f = v; a.i = __builtin_amdgcn_ds_swizzle(a.i, 0x101F); v = fmaxf(v, a.f);
  a.f = v; a.i = __builtin_amdgcn_ds_swizzle(a.i, 0x201F); v = fmaxf(v, a.f);
  return v;
}

// async global->LDS DMA, 16B/lane. LDS dest = wave-uniform base + lane*16.
__device__ __forceinline__ void async16(const u16* g, u16* l) {
  __builtin_amdgcn_global_load_lds(
      (const __attribute__((address_space(1))) u32*)g,
      (__attribute__((address_space(3))) u32*)l, 16, 0, 0);
}

// swizzled LDS index (elements): 64-col rows, 8 groups of 8
#define SWZ8(row, lg) (((row) << 6) + ((((lg) ^ ((row) & 7))) << 3))
// swizzled LDS index: 32-col rows, 4 groups of 8
#define SWZ4(row, lg) (((row) << 5) + ((((lg) ^ ((row) & 3))) << 3))

// ---------------- prep: split qkv weights fp32 -> bf16 hi/lo, permuted ----------------
__global__ __launch_bounds__(256) void prep_wq(
    const float* __restrict__ wq1, const float* __restrict__ wq2,
    u16* __restrict__ wh, u16* __restrict__ wl)
{
  int bx = blockIdx.x;                  // 0..4607
  int modal = bx / 2304, rowp = bx % 2304;
  int typ = rowp / 768, hd = rowp % 768;
  const float* W = (modal ? wq2 : wq1) + (size_t)(hd * 3 + typ) * EMB;
  size_t dst = (size_t)bx * EMB;
  int t = threadIdx.x;
  #pragma unroll
  for (int i = 0; i < 3; ++i) {
    int e = t + i * 256;
    float v = W[e];
    u16 h = f2bf(v);
    wh[dst + e] = h;
    wl[dst + e] = f2bf(v - bf2f(h));
  }
}

__global__ __launch_bounds__(256) void prep_wp(
    const float* __restrict__ wp1, const float* __restrict__ wp2,
    u16* __restrict__ wh)
{
  int bx = blockIdx.x;                  // 0..1535
  int modal = bx / 768, row = bx % 768;
  const float* W = (modal ? wp2 : wp1) + (size_t)row * EMB;
  size_t dst = (size_t)bx * EMB;
  int t = threadIdx.x;
  #pragma unroll
  for (int i = 0; i < 3; ++i) {
    int e = t + i * 256;
    wh[dst + e] = f2bf(W[e]);
  }
}

// ---------------- Kernel 1: LayerNorm (fp32 in) + hi/lo bf16 split ----------------
__global__ __launch_bounds__(256) void k_ln(
    const float* __restrict__ x1, const float* __restrict__ x2,
    const float* __restrict__ g1, const float* __restrict__ b1,
    const float* __restrict__ g2, const float* __restrict__ b2,
    u16* __restrict__ xn_hi, u16* __restrict__ xn_lo)
{
  int row = blockIdx.x;                 // 0..8191, modal-major
  int modal = row >> 12;
  const float* x = modal ? x2 : x1;
  const float* g = modal ? g2 : g1;
  const float* bb = modal ? b2 : b1;
  int r = row & (RPM - 1);
  const float* xr = x + (size_t)r * EMB;
  int t = threadIdx.x;
  float v0 = xr[t], v1 = xr[t + 256], v2 = xr[t + 512];
  float s = v0 + v1 + v2;
  float s2 = v0 * v0 + v1 * v1 + v2 * v2;
  #pragma unroll
  for (int m = 1; m < 64; m <<= 1) { s += __shfl_xor(s, m); s2 += __shfl_xor(s2, m); }
  __shared__ float ls[4], ls2[4];
  int w = t >> 6;
  if ((t & 63) == 0) { ls[w] = s; ls2[w] = s2; }
  __syncthreads();
  s = ls[0] + ls[1] + ls[2] + ls[3];
  s2 = ls2[0] + ls2[1] + ls2[2] + ls2[3];
  float mu = s * (1.0f / EMB);
  float var = s2 * (1.0f / EMB) - mu * mu;
  float rs = rsqrtf(var + 1e-5f);
  size_t base = (size_t)row * EMB;
  float vv[3] = { v0, v1, v2 };
  #pragma unroll
  for (int i = 0; i < 3; ++i) {
    int e = t + i * 256;
    float xn = (vv[i] - mu) * rs * g[e] + bb[e];
    u16 h = f2bf(xn);
    xn_hi[base + e] = h;
    xn_lo[base + e] = f2bf(xn - bf2f(h));
  }
}

// ---------------- Kernel 2: QKV GEMM — async DMA staging (m97-style) ----------------
// grid (32 row-tiles, 18 col-tiles, 2 modals), 256 thr. Tile 128x128, BK=32. 32KB LDS.
__global__ __launch_bounds__(256) void k_qkv(
    const u16* __restrict__ xn_hi, const u16* __restrict__ xn_lo,
    const u16* __restrict__ wqh, const u16* __restrict__ wql,
    const float* __restrict__ bq1, const float* __restrict__ bq2,
    u16* __restrict__ q_hi, u16* __restrict__ q_lo,
    u16* __restrict__ k_hi, u16* __restrict__ k_lo,
    u16* __restrict__ vT)
{
  int mt = blockIdx.x, ntile = blockIdx.y, modal = blockIdx.z;
  const float* BQ = modal ? bq2 : bq1;
  int typ = ntile / 6;            // 0=q 1=k 2=v
  int hd0 = (ntile % 6) * 128;

  __shared__ u16 Ah[128 * 32], Al[128 * 32], Bh[128 * 32], Bl[128 * 32];

  int tid = threadIdx.x, lane = tid & 63, w = tid >> 6;
  int wm = (w >> 1) * 64, wn = (w & 1) * 64;
  int lc = lane & 15, lq = lane >> 4;

  floatx4 acc[4][4] = {};
  size_t arow0 = (size_t)(modal * RPM + mt * 128) * EMB;
  size_t wrow0 = (size_t)(modal * 2304 + typ * 768 + hd0) * EMB;

  // DMA geometry: wave w stages rows [w*32, w*32+32), 2 segs of 16 rows.
  int rsub = lane >> 2;
  int g4 = (lane & 3) ^ (rsub & 3);
  const u16 *sA[2], *sAl[2], *sW[2], *sWl[2];
  int ldst[2];
  #pragma unroll
  for (int seg = 0; seg < 2; ++seg) {
    int row = w * 32 + seg * 16 + rsub;
    sA[seg]  = xn_hi + arow0 + (size_t)row * EMB + g4 * 8;
    sAl[seg] = xn_lo + arow0 + (size_t)row * EMB + g4 * 8;
    sW[seg]  = wqh + wrow0 + (size_t)row * EMB + g4 * 8;
    sWl[seg] = wql + wrow0 + (size_t)row * EMB + g4 * 8;
    ldst[seg] = (w * 32 + seg * 16) * 32;
  }

  for (int k0 = 0; k0 < EMB; k0 += 32) {
    #pragma unroll
    for (int seg = 0; seg < 2; ++seg) {
      async16(sA[seg] + k0, &Ah[ldst[seg]]);
      async16(sW[seg] + k0, &Bh[ldst[seg]]);
      if (typ != 2) {
        async16(sAl[seg] + k0, &Al[ldst[seg]]);
        async16(sWl[seg] + k0, &Bl[ldst[seg]]);
      }
    }
    __syncthreads();   // DMA drained

    shortx8 ah[4], al[4], wh[4], wl[4];
    #pragma unroll
    for (int i = 0; i < 4; ++i) {
      ah[i] = *(const shortx8*)&Ah[SWZ4(wm + i * 16 + lc, lq)];
      wh[i] = *(const shortx8*)&Bh[SWZ4(wn + i * 16 + lc, lq)];
      if (typ != 2) {
        al[i] = *(const shortx8*)&Al[SWZ4(wm + i * 16 + lc, lq)];
        wl[i] = *(const shortx8*)&Bl[SWZ4(wn + i * 16 + lc, lq)];
      }
    }
    #pragma unroll
    for (int i = 0; i < 4; ++i)
      #pragma unroll
      for (int jn = 0; jn < 4; ++jn) {
        acc[i][jn] = __builtin_amdgcn_mfma_f32_16x16x32_bf16(ah[i], wh[jn], acc[i][jn], 0, 0, 0);
        if (typ != 2) {
          acc[i][jn] = __builtin_amdgcn_mfma_f32_16x16x32_bf16(al[i], wh[jn], acc[i][jn], 0, 0, 0);
          acc[i][jn] = __builtin_amdgcn_mfma_f32_16x16x32_bf16(ah[i], wl[jn], acc[i][jn], 0, 0, 0);
        }
      }
    __syncthreads();   // reads done before next DMA overwrites
  }

  #pragma unroll
  for (int i = 0; i < 4; ++i) {
    int mrow0 = mt * 128 + wm + i * 16 + lq * 4;
    #pragma unroll
    for (int jn = 0; jn < 4; ++jn) {
      int colp = hd0 + wn + jn * 16 + lc;          // hd index [0,768)
      int h = colp >> 6, d = colp & 63;
      float bias = BQ[colp * 3 + typ];
      #pragma unroll
      for (int r = 0; r < 4; ++r) {
        int mrow = mrow0 + r;
        int b = mrow >> 11, nq = mrow & (SEQ - 1);
        int uu = modal * 24 + b * 12 + h;
        float val = acc[i][jn][r] + bias;
        if (typ == 0) {
          size_t o = ((size_t)uu * SEQ + nq) * HDIM + d;
          u16 hh = f2bf(val); q_hi[o] = hh; q_lo[o] = f2bf(val - bf2f(hh));
        } else if (typ == 1) {
          size_t o = ((size_t)uu * SEQ + nq) * HDIM + d;
          u16 hh = f2bf(val); k_hi[o] = hh; k_lo[o] = f2bf(val - bf2f(hh));
        } else {
          vT[((size_t)uu * HDIM + d) * SEQ + nq] = f2bf(val);
        }
      }
    }
  }
}

// ---------------- Kernel 3: flash attention — single-buffer DMA, 4 blocks/CU ----------------
// grid (48 units, 16 q-tiles): XCD = u%8 fixed -> per-unit K/V L2-resident.
// LDS: KV 24KB + Ps 16KB = 40KB -> 4 blocks/CU; cross-block overlap hides drains.
__global__ __launch_bounds__(256, 4) void k_attn(
    const u16* __restrict__ q_hi, const u16* __restrict__ q_lo,
    const u16* __restrict__ k_hi, const u16* __restrict__ k_lo,
    const u16* __restrict__ vT, u16* __restrict__ attn_out)
{
  int u = blockIdx.x, qt = blockIdx.y;
  __shared__ u16 Kh[64 * 64], Kl[64 * 64], Vs[64 * 64];   // swizzled
  __shared__ u16 Ps[4][32 * 64];                          // swizzled, wave-private

  int tid = threadIdx.x, lane = tid & 63, w = tid >> 6;
  int lc = lane & 15, lq = lane >> 4;
  u16* psw = &Ps[w][0];

  // Q fragments: 2 m-tiles x 2 k-slices, hi+lo (A-layout: m=lc, k=lq*8+j)
  shortx8 qh[2][2], ql[2][2];
  #pragma unroll
  for (int mi = 0; mi < 2; ++mi) {
    size_t qb = ((size_t)u * SEQ + qt * 128 + w * 32 + mi * 16 + lc) * HDIM + lq * 8;
    qh[mi][0] = *(const shortx8*)(q_hi + qb);
    qh[mi][1] = *(const shortx8*)(q_hi + qb + 32);
    ql[mi][0] = *(const shortx8*)(q_lo + qb);
    ql[mi][1] = *(const shortx8*)(q_lo + qb + 32);
  }

  shortx8 ONES;
  #pragma unroll
  for (int j = 0; j < 8; ++j) ONES[j] = (short)0x3F80;  // bf16 1.0

  floatx4 O[2][4] = {};
  floatx4 Osum[2] = {};
  float mrow[2][4];
  #pragma unroll
  for (int mi = 0; mi < 2; ++mi)
    #pragma unroll
    for (int r = 0; r < 4; ++r) mrow[mi][r] = -1e30f;
  const float Cs = 11.5415603271f;  // 8 * log2(e)

  // DMA geometry: wave w stages rows [w*16, w*16+16), 2 segs of 8 rows.
  int rsub = lane >> 3;
  int g8 = (lane & 7) ^ rsub;
  const u16 *sKh[2], *sKl[2], *sV[2];
  int ldst[2];
  #pragma unroll
  for (int seg = 0; seg < 2; ++seg) {
    int row = w * 16 + seg * 8 + rsub;
    sKh[seg] = k_hi + ((size_t)u * SEQ + row) * HDIM + g8 * 8;
    sKl[seg] = k_lo + ((size_t)u * SEQ + row) * HDIM + g8 * 8;
    sV[seg]  = vT + ((size_t)u * HDIM + row) * SEQ + g8 * 8;
    ldst[seg] = (w * 16 + seg * 8) * 64;
  }

  for (int kc = 0; kc < SEQ; kc += 64) {
    #pragma unroll
    for (int seg = 0; seg < 2; ++seg) {
      async16(sKh[seg] + (size_t)kc * HDIM, &Kh[ldst[seg]]);
      async16(sKl[seg] + (size_t)kc * HDIM, &Kl[ldst[seg]]);
      async16(sV[seg] + kc,                 &Vs[ldst[seg]]);
    }
    __syncthreads();   // DMA drained; other blocks' waves compute through this

    // S = Q.K^T, 3-pass hi/lo, swizzled B-frag reads
    floatx4 S[2][4] = {};
    #pragma unroll
    for (int nt = 0; nt < 4; ++nt)
      #pragma unroll
      for (int ks = 0; ks < 2; ++ks) {
        shortx8 kf = *(const shortx8*)&Kh[SWZ8(nt * 16 + lc, ks * 4 + lq)];
        shortx8 lf = *(const shortx8*)&Kl[SWZ8(nt * 16 + lc, ks * 4 + lq)];
        #pragma unroll
        for (int mi = 0; mi < 2; ++mi) {
          S[mi][nt] = __builtin_amdgcn_mfma_f32_16x16x32_bf16(qh[mi][ks], kf, S[mi][nt], 0, 0, 0);
          S[mi][nt] = __builtin_amdgcn_mfma_f32_16x16x32_bf16(ql[mi][ks], kf, S[mi][nt], 0, 0, 0);
          S[mi][nt] = __builtin_amdgcn_mfma_f32_16x16x32_bf16(qh[mi][ks], lf, S[mi][nt], 0, 0, 0);
        }
      }

    // online softmax; l via ones-column MFMA (Osum)
    #pragma unroll
    for (int mi = 0; mi < 2; ++mi) {
      float alpha[4];
      #pragma unroll
      for (int r = 0; r < 4; ++r) {
        float mc = fmaxf(fmaxf(S[mi][0][r], S[mi][1][r]), fmaxf(S[mi][2][r], S[mi][3][r]));
        mc = swz_max16(mc);
        float mn = fmaxf(mrow[mi][r], mc * Cs);
        alpha[r] = __builtin_amdgcn_exp2f(mrow[mi][r] - mn);
        mrow[mi][r] = mn;
      }
      #pragma unroll
      for (int nt = 0; nt < 4; ++nt)
        #pragma unroll
        for (int r = 0; r < 4; ++r) {
          float e = __builtin_amdgcn_exp2f(fmaf(S[mi][nt][r], Cs, -mrow[mi][r]));
          int prow = mi * 16 + lq * 4 + r;
          int pcol = nt * 16 + lc;
          psw[(prow << 6) + ((((pcol >> 3) ^ (prow & 7))) << 3) + (pcol & 7)] = f2bf_tr(e);
        }
      #pragma unroll
      for (int nt = 0; nt < 4; ++nt)
        #pragma unroll
        for (int r = 0; r < 4; ++r) O[mi][nt][r] *= alpha[r];
      #pragma unroll
      for (int r = 0; r < 4; ++r) Osum[mi][r] *= alpha[r];
    }

    // PV (Ps wave-private; DS ops in-order within wave)
    #pragma unroll
    for (int ks = 0; ks < 2; ++ks) {
      shortx8 pf[2];
      #pragma unroll
      for (int mi = 0; mi < 2; ++mi)
        pf[mi] = *(const shortx8*)&psw[SWZ8(mi * 16 + lc, ks * 4 + lq)];
      #pragma unroll
      for (int nt = 0; nt < 4; ++nt) {
        shortx8 vf = *(const shortx8*)&Vs[SWZ8(nt * 16 + lc, ks * 4 + lq)];
        #pragma unroll
        for (int mi = 0; mi < 2; ++mi)
          O[mi][nt] = __builtin_amdgcn_mfma_f32_16x16x32_bf16(pf[mi], vf, O[mi][nt], 0, 0, 0);
      }
      #pragma unroll
      for (int mi = 0; mi < 2; ++mi)
        Osum[mi] = __builtin_amdgcn_mfma_f32_16x16x32_bf16(pf[mi], ONES, Osum[mi], 0, 0, 0);
    }
    __syncthreads();   // all waves done reading KV before next chunk's DMA
  }

  int modal = u / 24, b2 = (u / 12) & 1, h = u % 12;
  #pragma unroll
  for (int mi = 0; mi < 2; ++mi)
    #pragma unroll
    for (int r = 0; r < 4; ++r) {
      float rl = __builtin_amdgcn_rcpf(Osum[mi][r]);
      int qrow = qt * 128 + w * 32 + mi * 16 + lq * 4 + r;
      size_t ob = ((size_t)(modal * RPM + b2 * SEQ + qrow)) * EMB + h * 64 + lc;
      #pragma unroll
      for (int nt = 0; nt < 4; ++nt)
        attn_out[ob + nt * 16] = f2bf(O[mi][nt][r] * rl);
    }
}

// ---------------- Kernel 4: proj GEMM — async DMA staging ----------------
// grid (32 row-tiles, 6 col-tiles, 2 modals), 16KB LDS
__global__ __launch_bounds__(256) void k_proj(
    const u16* __restrict__ ao, const u16* __restrict__ wph,
    const float* __restrict__ x1, const float* __restrict__ x2,
    const float* __restrict__ bp1, const float* __restrict__ bp2,
    float* __restrict__ out)
{
  int mt = blockIdx.x, ntile = blockIdx.y, modal = blockIdx.z;
  const float* BP = modal ? bp2 : bp1;
  const float* x  = modal ? x2 : x1;

  __shared__ u16 As[128 * 32], Ws[128 * 32];
  int tid = threadIdx.x, lane = tid & 63, w = tid >> 6;
  int wm = (w >> 1) * 64, wn = (w & 1) * 64;
  int lc = lane & 15, lq = lane >> 4;

  floatx4 acc[4][4] = {};
  size_t arow0 = (size_t)(modal * RPM + mt * 128) * EMB;
  int col0 = ntile * 128;
  size_t wrow0 = (size_t)(modal * 768 + col0) * EMB;

  int rsub = lane >> 2;
  int g4 = (lane & 3) ^ (rsub & 3);
  const u16 *sA[2], *sW[2];
  int ldst[2];
  #pragma unroll
  for (int seg = 0; seg < 2; ++seg) {
    int row = w * 32 + seg * 16 + rsub;
    sA[seg] = ao + arow0 + (size_t)row * EMB + g4 * 8;
    sW[seg] = wph + wrow0 + (size_t)row * EMB + g4 * 8;
    ldst[seg] = (w * 32 + seg * 16) * 32;
  }

  for (int k0 = 0; k0 < EMB; k0 += 32) {
    #pragma unroll
    for (int seg = 0; seg < 2; ++seg) {
      async16(sA[seg] + k0, &As[ldst[seg]]);
      async16(sW[seg] + k0, &Ws[ldst[seg]]);
    }
    __syncthreads();

    shortx8 af[4], wf[4];
    #pragma unroll
    for (int i = 0; i < 4; ++i) {
      af[i] = *(const shortx8*)&As[SWZ4(wm + i * 16 + lc, lq)];
      wf[i] = *(const shortx8*)&Ws[SWZ4(wn + i * 16 + lc, lq)];
    }
    #pragma unroll
    for (int i = 0; i < 4; ++i)
      #pragma unroll
      for (int jn = 0; jn < 4; ++jn)
        acc[i][jn] = __builtin_amdgcn_mfma_f32_16x16x32_bf16(af[i], wf[jn], acc[i][jn], 0, 0, 0);
    __syncthreads();
  }

  #pragma unroll
  for (int i = 0; i < 4; ++i) {
    int mrow0 = mt * 128 + wm + i * 16 + lq * 4;
    #pragma unroll
    for (int jn = 0; jn < 4; ++jn) {
      int col = col0 + wn + jn * 16 + lc;
      float bias = BP[col];
      #pragma unroll
      for (int r = 0; r < 4; ++r) {
        int mrow = mrow0 + r;
        float val = acc[i][jn][r] + bias + x[(size_t)mrow * EMB + col];
        out[((size_t)(modal * RPM + mrow)) * EMB + col] = val;
      }
    }
  }
}

extern "C" void kernel_launch(void* const* d_in, const int* in_sizes, int n_in,
                              void* d_out, int out_size, void* d_ws, size_t ws_size,
                              hipStream_t stream) {
  const float* modal1 = (const float*)d_in[0];
  const float* modal2 = (const float*)d_in[1];
  const float* ln1_g  = (const float*)d_in[2];
  const float* ln1_b  = (const float*)d_in[3];
  const float* w_qkv1 = (const float*)d_in[4];
  const float* b_qkv1 = (const float*)d_in[5];
  const float* w_proj1= (const float*)d_in[6];
  const float* b_proj1= (const float*)d_in[7];
  const float* ln2_g  = (const float*)d_in[8];
  const float* ln2_b  = (const float*)d_in[9];
  const float* w_qkv2 = (const float*)d_in[10];
  const float* b_qkv2 = (const float*)d_in[11];
  const float* w_proj2= (const float*)d_in[12];
  const float* b_proj2= (const float*)d_in[13];
  float* out = (float*)d_out;

  const size_t BUFE = (size_t)NROW * EMB;       // 6291456 elems
  const size_t WQE  = (size_t)2 * 2304 * EMB;   // 3538944 elems
  u16* xn_hi = (u16*)d_ws;
  u16* xn_lo = xn_hi + BUFE;
  u16* q_hi  = xn_lo + BUFE;
  u16* q_lo  = q_hi + BUFE;
  u16* k_hi  = q_lo + BUFE;
  u16* k_lo  = k_hi + BUFE;
  u16* vT    = k_lo + BUFE;
  u16* wq_h  = vT + BUFE;
  u16* wq_l  = wq_h + WQE;
  u16* attn  = xn_hi;   // xn dead after k_qkv
  u16* wp_h  = q_lo;    // q_lo dead after k_attn

  prep_wq<<<4608, 256, 0, stream>>>(w_qkv1, w_qkv2, wq_h, wq_l);
  k_ln<<<NROW, 256, 0, stream>>>(modal1, modal2, ln1_g, ln1_b, ln2_g, ln2_b, xn_hi, xn_lo);
  dim3 g2(32, 18, 2);
  k_qkv<<<g2, 256, 0, stream>>>(xn_hi, xn_lo, wq_h, wq_l, b_qkv1, b_qkv2,
                                q_hi, q_lo, k_hi, k_lo, vT);
  dim3 g3(48, 16);   // u fastest -> XCD = u%8 fixed across qt
  k_attn<<<g3, 256, 0, stream>>>(q_hi, q_lo, k_hi, k_lo, vT, attn);
  prep_wp<<<1536, 256, 0, stream>>>(w_proj1, w_proj2, wp_h);
  dim3 g4(32, 6, 2);
  k_proj<<<g4, 256, 0, stream>>>(attn, wp_h, modal1, modal2, b_proj1, b_proj2, out);
}

// Round 9
// 427.375 us; speedup vs baseline: 1.7127x; 1.7127x over previous
//
#include <hip/hip_runtime.h>
#include <hip/hip_bf16.h>

// History: r4 407us (k_attn 185 = best structure: inline staging, self-staggered).
// r5 XCD grid cut FETCH 160->49MB (keep) but reg-prefetch regressed (compiler sank it).
// r6 direct-global = L1 request wall. r7 DMA dbuf = vmcnt serialization + 2 blk/CU.
// r8 launch_bounds(256,4) -> VGPR 64 -> accumulators spilled to scratch (WRITE 63MB,
// FETCH 792MB) = disaster. NEVER cap a kernel living near the VGPR budget.
// r9 = r4 staging + XCD grid + XOR-swizzled unpadded LDS (40KB -> 4 blk/CU natural).

typedef unsigned short u16;
typedef unsigned int   u32;
typedef __attribute__((ext_vector_type(4))) float          floatx4;
typedef __attribute__((ext_vector_type(8))) short          shortx8;

#define EMB   768
#define SEQ   2048
#define NHEAD 12
#define HDIM  64
#define RPM   4096   // rows per modal (B*N)
#define NROW  8192   // total rows (2 modals)
#define NUNIT 48     // modal*B*H units

__device__ __forceinline__ float bf2f(u16 h) {
  union { u32 u; float f; } v; v.u = ((u32)h) << 16; return v.f;
}
__device__ __forceinline__ u16 f2bf(float f) {            // RNE
  union { float f; u32 u; } v; v.f = f;
  u32 r = v.u + 0x7fffu + ((v.u >> 16) & 1u);
  return (u16)(r >> 16);
}
__device__ __forceinline__ u16 f2bf_tr(float f) {         // truncate (P in [0,1])
  union { float f; u32 u; } v; v.f = f;
  return (u16)(v.u >> 16);
}
__device__ __forceinline__ float swz_max16(float v) {     // max over 16-lane group
  union { float f; int i; } a;
  a.f = v; a.i = __builtin_amdgcn_ds_swizzle(a.i, 0x041F); v = fmaxf(v, a.f);
  a.f = v; a.i = __builtin_amdgcn_ds_swizzle(a.i, 0x081F); v = fmaxf(v, a.f);
  a.f = v; a.i = __builtin_amdgcn_ds_swizzle(a.i, 0x101F); v = fmaxf(v, a.f);
  a.f = v; a.i = __builtin_amdgcn_ds_swizzle(a.i, 0x201F); v = fmaxf(v, a.f);
  return v;
}

// async global->LDS DMA, 16B/lane. LDS dest = wave-uniform base + lane*16.
__device__ __forceinline__ void async16(const u16* g, u16* l) {
  __builtin_amdgcn_global_load_lds(
      (const __attribute__((address_space(1))) u32*)g,
      (__attribute__((address_space(3))) u32*)l, 16, 0, 0);
}

// swizzled LDS index (elements): 64-col rows, 8 groups of 8
#define SWZ8(row, lg) (((row) << 6) + ((((lg) ^ ((row) & 7))) << 3))
// swizzled LDS index: 32-col rows, 4 groups of 8
#define SWZ4(row, lg) (((row) << 5) + ((((lg) ^ ((row) & 3))) << 3))

// ---------------- prep: split qkv weights fp32 -> bf16 hi/lo, permuted ----------------
__global__ __launch_bounds__(256) void prep_wq(
    const float* __restrict__ wq1, const float* __restrict__ wq2,
    u16* __restrict__ wh, u16* __restrict__ wl)
{
  int bx = blockIdx.x;                  // 0..4607
  int modal = bx / 2304, rowp = bx % 2304;
  int typ = rowp / 768, hd = rowp % 768;
  const float* W = (modal ? wq2 : wq1) + (size_t)(hd * 3 + typ) * EMB;
  size_t dst = (size_t)bx * EMB;
  int t = threadIdx.x;
  #pragma unroll
  for (int i = 0; i < 3; ++i) {
    int e = t + i * 256;
    float v = W[e];
    u16 h = f2bf(v);
    wh[dst + e] = h;
    wl[dst + e] = f2bf(v - bf2f(h));
  }
}

__global__ __launch_bounds__(256) void prep_wp(
    const float* __restrict__ wp1, const float* __restrict__ wp2,
    u16* __restrict__ wh)
{
  int bx = blockIdx.x;                  // 0..1535
  int modal = bx / 768, row = bx % 768;
  const float* W = (modal ? wp2 : wp1) + (size_t)row * EMB;
  size_t dst = (size_t)bx * EMB;
  int t = threadIdx.x;
  #pragma unroll
  for (int i = 0; i < 3; ++i) {
    int e = t + i * 256;
    wh[dst + e] = f2bf(W[e]);
  }
}

// ---------------- Kernel 1: LayerNorm (fp32 in) + hi/lo bf16 split ----------------
__global__ __launch_bounds__(256) void k_ln(
    const float* __restrict__ x1, const float* __restrict__ x2,
    const float* __restrict__ g1, const float* __restrict__ b1,
    const float* __restrict__ g2, const float* __restrict__ b2,
    u16* __restrict__ xn_hi, u16* __restrict__ xn_lo)
{
  int row = blockIdx.x;                 // 0..8191, modal-major
  int modal = row >> 12;
  const float* x = modal ? x2 : x1;
  const float* g = modal ? g2 : g1;
  const float* bb = modal ? b2 : b1;
  int r = row & (RPM - 1);
  const float* xr = x + (size_t)r * EMB;
  int t = threadIdx.x;
  float v0 = xr[t], v1 = xr[t + 256], v2 = xr[t + 512];
  float s = v0 + v1 + v2;
  float s2 = v0 * v0 + v1 * v1 + v2 * v2;
  #pragma unroll
  for (int m = 1; m < 64; m <<= 1) { s += __shfl_xor(s, m); s2 += __shfl_xor(s2, m); }
  __shared__ float ls[4], ls2[4];
  int w = t >> 6;
  if ((t & 63) == 0) { ls[w] = s; ls2[w] = s2; }
  __syncthreads();
  s = ls[0] + ls[1] + ls[2] + ls[3];
  s2 = ls2[0] + ls2[1] + ls2[2] + ls2[3];
  float mu = s * (1.0f / EMB);
  float var = s2 * (1.0f / EMB) - mu * mu;
  float rs = rsqrtf(var + 1e-5f);
  size_t base = (size_t)row * EMB;
  float vv[3] = { v0, v1, v2 };
  #pragma unroll
  for (int i = 0; i < 3; ++i) {
    int e = t + i * 256;
    float xn = (vv[i] - mu) * rs * g[e] + bb[e];
    u16 h = f2bf(xn);
    xn_hi[base + e] = h;
    xn_lo[base + e] = f2bf(xn - bf2f(h));
  }
}

// ---------------- Kernel 2: QKV GEMM — async DMA staging (m97-style) ----------------
// grid (32 row-tiles, 18 col-tiles, 2 modals), 256 thr. Tile 128x128, BK=32. 32KB LDS.
__global__ __launch_bounds__(256) void k_qkv(
    const u16* __restrict__ xn_hi, const u16* __restrict__ xn_lo,
    const u16* __restrict__ wqh, const u16* __restrict__ wql,
    const float* __restrict__ bq1, const float* __restrict__ bq2,
    u16* __restrict__ q_hi, u16* __restrict__ q_lo,
    u16* __restrict__ k_hi, u16* __restrict__ k_lo,
    u16* __restrict__ vT)
{
  int mt = blockIdx.x, ntile = blockIdx.y, modal = blockIdx.z;
  const float* BQ = modal ? bq2 : bq1;
  int typ = ntile / 6;            // 0=q 1=k 2=v
  int hd0 = (ntile % 6) * 128;

  __shared__ u16 Ah[128 * 32], Al[128 * 32], Bh[128 * 32], Bl[128 * 32];

  int tid = threadIdx.x, lane = tid & 63, w = tid >> 6;
  int wm = (w >> 1) * 64, wn = (w & 1) * 64;
  int lc = lane & 15, lq = lane >> 4;

  floatx4 acc[4][4] = {};
  size_t arow0 = (size_t)(modal * RPM + mt * 128) * EMB;
  size_t wrow0 = (size_t)(modal * 2304 + typ * 768 + hd0) * EMB;

  // DMA geometry: wave w stages rows [w*32, w*32+32), 2 segs of 16 rows.
  int rsub = lane >> 2;
  int g4 = (lane & 3) ^ (rsub & 3);
  const u16 *sA[2], *sAl[2], *sW[2], *sWl[2];
  int ldst[2];
  #pragma unroll
  for (int seg = 0; seg < 2; ++seg) {
    int row = w * 32 + seg * 16 + rsub;
    sA[seg]  = xn_hi + arow0 + (size_t)row * EMB + g4 * 8;
    sAl[seg] = xn_lo + arow0 + (size_t)row * EMB + g4 * 8;
    sW[seg]  = wqh + wrow0 + (size_t)row * EMB + g4 * 8;
    sWl[seg] = wql + wrow0 + (size_t)row * EMB + g4 * 8;
    ldst[seg] = (w * 32 + seg * 16) * 32;
  }

  for (int k0 = 0; k0 < EMB; k0 += 32) {
    #pragma unroll
    for (int seg = 0; seg < 2; ++seg) {
      async16(sA[seg] + k0, &Ah[ldst[seg]]);
      async16(sW[seg] + k0, &Bh[ldst[seg]]);
      if (typ != 2) {
        async16(sAl[seg] + k0, &Al[ldst[seg]]);
        async16(sWl[seg] + k0, &Bl[ldst[seg]]);
      }
    }
    __syncthreads();   // DMA drained

    shortx8 ah[4], al[4], wh[4], wl[4];
    #pragma unroll
    for (int i = 0; i < 4; ++i) {
      ah[i] = *(const shortx8*)&Ah[SWZ4(wm + i * 16 + lc, lq)];
      wh[i] = *(const shortx8*)&Bh[SWZ4(wn + i * 16 + lc, lq)];
      if (typ != 2) {
        al[i] = *(const shortx8*)&Al[SWZ4(wm + i * 16 + lc, lq)];
        wl[i] = *(const shortx8*)&Bl[SWZ4(wn + i * 16 + lc, lq)];
      }
    }
    #pragma unroll
    for (int i = 0; i < 4; ++i)
      #pragma unroll
      for (int jn = 0; jn < 4; ++jn) {
        acc[i][jn] = __builtin_amdgcn_mfma_f32_16x16x32_bf16(ah[i], wh[jn], acc[i][jn], 0, 0, 0);
        if (typ != 2) {
          acc[i][jn] = __builtin_amdgcn_mfma_f32_16x16x32_bf16(al[i], wh[jn], acc[i][jn], 0, 0, 0);
          acc[i][jn] = __builtin_amdgcn_mfma_f32_16x16x32_bf16(ah[i], wl[jn], acc[i][jn], 0, 0, 0);
        }
      }
    __syncthreads();   // reads done before next DMA overwrites
  }

  #pragma unroll
  for (int i = 0; i < 4; ++i) {
    int mrow0 = mt * 128 + wm + i * 16 + lq * 4;
    #pragma unroll
    for (int jn = 0; jn < 4; ++jn) {
      int colp = hd0 + wn + jn * 16 + lc;          // hd index [0,768)
      int h = colp >> 6, d = colp & 63;
      float bias = BQ[colp * 3 + typ];
      #pragma unroll
      for (int r = 0; r < 4; ++r) {
        int mrow = mrow0 + r;
        int b = mrow >> 11, nq = mrow & (SEQ - 1);
        int uu = modal * 24 + b * 12 + h;
        float val = acc[i][jn][r] + bias;
        if (typ == 0) {
          size_t o = ((size_t)uu * SEQ + nq) * HDIM + d;
          u16 hh = f2bf(val); q_hi[o] = hh; q_lo[o] = f2bf(val - bf2f(hh));
        } else if (typ == 1) {
          size_t o = ((size_t)uu * SEQ + nq) * HDIM + d;
          u16 hh = f2bf(val); k_hi[o] = hh; k_lo[o] = f2bf(val - bf2f(hh));
        } else {
          vT[((size_t)uu * HDIM + d) * SEQ + nq] = f2bf(val);
        }
      }
    }
  }
}

// ---------------- Kernel 3: flash attention — r4 staging + swizzle + XCD grid ----------------
// grid (48 units, 16 q-tiles): XCD = u%8 fixed -> per-unit K/V L2-resident.
// Plain inline load->LDS store (waves self-stagger on vmcnt, no prefetch games).
// Swizzled unpadded tiles: KV 24KB + Ps 16KB = 40KB -> 4 blocks/CU at VGPR~124.
__global__ __launch_bounds__(256) void k_attn(
    const u16* __restrict__ q_hi, const u16* __restrict__ q_lo,
    const u16* __restrict__ k_hi, const u16* __restrict__ k_lo,
    const u16* __restrict__ vT, u16* __restrict__ attn_out)
{
  int u = blockIdx.x, qt = blockIdx.y;
  __shared__ u16 Kh[64 * 64], Kl[64 * 64], Vs[64 * 64];   // swizzled
  __shared__ u16 Ps[4][32 * 64];                          // swizzled, wave-private

  int tid = threadIdx.x, lane = tid & 63, w = tid >> 6;
  int lc = lane & 15, lq = lane >> 4;
  u16* psw = &Ps[w][0];

  // Q fragments: 2 m-tiles x 2 k-slices, hi+lo (A-layout: m=lc, k=lq*8+j)
  shortx8 qh[2][2], ql[2][2];
  #pragma unroll
  for (int mi = 0; mi < 2; ++mi) {
    size_t qb = ((size_t)u * SEQ + qt * 128 + w * 32 + mi * 16 + lc) * HDIM + lq * 8;
    qh[mi][0] = *(const shortx8*)(q_hi + qb);
    qh[mi][1] = *(const shortx8*)(q_hi + qb + 32);
    ql[mi][0] = *(const shortx8*)(q_lo + qb);
    ql[mi][1] = *(const shortx8*)(q_lo + qb + 32);
  }

  shortx8 ONES;
  #pragma unroll
  for (int j = 0; j < 8; ++j) ONES[j] = (short)0x3F80;  // bf16 1.0

  floatx4 O[2][4] = {};
  floatx4 Osum[2] = {};
  float mrow[2][4];
  #pragma unroll
  for (int mi = 0; mi < 2; ++mi)
    #pragma unroll
    for (int r = 0; r < 4; ++r) mrow[mi][r] = -1e30f;
  const float Cs = 11.5415603271f;  // 8 * log2(e)

  // staging geometry: 512 chunks of 8 elems (64 rows x 8 groups); swizzled dest
  int c0 = tid, c1 = tid + 256;
  int r0 = c0 >> 3, g0 = c0 & 7;
  int r1 = c1 >> 3, g1 = c1 & 7;
  const u16* khp0 = k_hi + ((size_t)u * SEQ + r0) * HDIM + g0 * 8;
  const u16* khp1 = k_hi + ((size_t)u * SEQ + r1) * HDIM + g1 * 8;
  const u16* klp0 = k_lo + ((size_t)u * SEQ + r0) * HDIM + g0 * 8;
  const u16* klp1 = k_lo + ((size_t)u * SEQ + r1) * HDIM + g1 * 8;
  const u16* vp0  = vT + ((size_t)u * HDIM + r0) * SEQ + g0 * 8;
  const u16* vp1  = vT + ((size_t)u * HDIM + r1) * SEQ + g1 * 8;
  int d0 = SWZ8(r0, g0), d1 = SWZ8(r1, g1);

  for (int kc = 0; kc < SEQ; kc += 64) {
    *(shortx8*)&Kh[d0] = *(const shortx8*)(khp0 + (size_t)kc * HDIM);
    *(shortx8*)&Kh[d1] = *(const shortx8*)(khp1 + (size_t)kc * HDIM);
    *(shortx8*)&Kl[d0] = *(const shortx8*)(klp0 + (size_t)kc * HDIM);
    *(shortx8*)&Kl[d1] = *(const shortx8*)(klp1 + (size_t)kc * HDIM);
    *(shortx8*)&Vs[d0] = *(const shortx8*)(vp0 + kc);
    *(shortx8*)&Vs[d1] = *(const shortx8*)(vp1 + kc);
    __syncthreads();

    // S = Q.K^T, 3-pass hi/lo, swizzled B-frag reads
    floatx4 S[2][4] = {};
    #pragma unroll
    for (int nt = 0; nt < 4; ++nt)
      #pragma unroll
      for (int ks = 0; ks < 2; ++ks) {
        shortx8 kf = *(const shortx8*)&Kh[SWZ8(nt * 16 + lc, ks * 4 + lq)];
        shortx8 lf = *(const shortx8*)&Kl[SWZ8(nt * 16 + lc, ks * 4 + lq)];
        #pragma unroll
        for (int mi = 0; mi < 2; ++mi) {
          S[mi][nt] = __builtin_amdgcn_mfma_f32_16x16x32_bf16(qh[mi][ks], kf, S[mi][nt], 0, 0, 0);
          S[mi][nt] = __builtin_amdgcn_mfma_f32_16x16x32_bf16(ql[mi][ks], kf, S[mi][nt], 0, 0, 0);
          S[mi][nt] = __builtin_amdgcn_mfma_f32_16x16x32_bf16(qh[mi][ks], lf, S[mi][nt], 0, 0, 0);
        }
      }

    // online softmax; l via ones-column MFMA (Osum)
    #pragma unroll
    for (int mi = 0; mi < 2; ++mi) {
      float alpha[4];
      #pragma unroll
      for (int r = 0; r < 4; ++r) {
        float mc = fmaxf(fmaxf(S[mi][0][r], S[mi][1][r]), fmaxf(S[mi][2][r], S[mi][3][r]));
        mc = swz_max16(mc);
        float mn = fmaxf(mrow[mi][r], mc * Cs);
        alpha[r] = __builtin_amdgcn_exp2f(mrow[mi][r] - mn);
        mrow[mi][r] = mn;
      }
      #pragma unroll
      for (int nt = 0; nt < 4; ++nt)
        #pragma unroll
        for (int r = 0; r < 4; ++r) {
          float e = __builtin_amdgcn_exp2f(fmaf(S[mi][nt][r], Cs, -mrow[mi][r]));
          int prow = mi * 16 + lq * 4 + r;
          int pcol = nt * 16 + lc;
          psw[(prow << 6) + ((((pcol >> 3) ^ (prow & 7))) << 3) + (pcol & 7)] = f2bf_tr(e);
        }
      #pragma unroll
      for (int nt = 0; nt < 4; ++nt)
        #pragma unroll
        for (int r = 0; r < 4; ++r) O[mi][nt][r] *= alpha[r];
      #pragma unroll
      for (int r = 0; r < 4; ++r) Osum[mi][r] *= alpha[r];
    }

    // PV (Ps wave-private; DS ops in-order within wave)
    #pragma unroll
    for (int ks = 0; ks < 2; ++ks) {
      shortx8 pf[2];
      #pragma unroll
      for (int mi = 0; mi < 2; ++mi)
        pf[mi] = *(const shortx8*)&psw[SWZ8(mi * 16 + lc, ks * 4 + lq)];
      #pragma unroll
      for (int nt = 0; nt < 4; ++nt) {
        shortx8 vf = *(const shortx8*)&Vs[SWZ8(nt * 16 + lc, ks * 4 + lq)];
        #pragma unroll
        for (int mi = 0; mi < 2; ++mi)
          O[mi][nt] = __builtin_amdgcn_mfma_f32_16x16x32_bf16(pf[mi], vf, O[mi][nt], 0, 0, 0);
      }
      #pragma unroll
      for (int mi = 0; mi < 2; ++mi)
        Osum[mi] = __builtin_amdgcn_mfma_f32_16x16x32_bf16(pf[mi], ONES, Osum[mi], 0, 0, 0);
    }
    __syncthreads();
  }

  int modal = u / 24, b2 = (u / 12) & 1, h = u % 12;
  #pragma unroll
  for (int mi = 0; mi < 2; ++mi)
    #pragma unroll
    for (int r = 0; r < 4; ++r) {
      float rl = __builtin_amdgcn_rcpf(Osum[mi][r]);
      int qrow = qt * 128 + w * 32 + mi * 16 + lq * 4 + r;
      size_t ob = ((size_t)(modal * RPM + b2 * SEQ + qrow)) * EMB + h * 64 + lc;
      #pragma unroll
      for (int nt = 0; nt < 4; ++nt)
        attn_out[ob + nt * 16] = f2bf(O[mi][nt][r] * rl);
    }
}

// ---------------- Kernel 4: proj GEMM — async DMA staging ----------------
// grid (32 row-tiles, 6 col-tiles, 2 modals), 16KB LDS
__global__ __launch_bounds__(256) void k_proj(
    const u16* __restrict__ ao, const u16* __restrict__ wph,
    const float* __restrict__ x1, const float* __restrict__ x2,
    const float* __restrict__ bp1, const float* __restrict__ bp2,
    float* __restrict__ out)
{
  int mt = blockIdx.x, ntile = blockIdx.y, modal = blockIdx.z;
  const float* BP = modal ? bp2 : bp1;
  const float* x  = modal ? x2 : x1;

  __shared__ u16 As[128 * 32], Ws[128 * 32];
  int tid = threadIdx.x, lane = tid & 63, w = tid >> 6;
  int wm = (w >> 1) * 64, wn = (w & 1) * 64;
  int lc = lane & 15, lq = lane >> 4;

  floatx4 acc[4][4] = {};
  size_t arow0 = (size_t)(modal * RPM + mt * 128) * EMB;
  int col0 = ntile * 128;
  size_t wrow0 = (size_t)(modal * 768 + col0) * EMB;

  int rsub = lane >> 2;
  int g4 = (lane & 3) ^ (rsub & 3);
  const u16 *sA[2], *sW[2];
  int ldst[2];
  #pragma unroll
  for (int seg = 0; seg < 2; ++seg) {
    int row = w * 32 + seg * 16 + rsub;
    sA[seg] = ao + arow0 + (size_t)row * EMB + g4 * 8;
    sW[seg] = wph + wrow0 + (size_t)row * EMB + g4 * 8;
    ldst[seg] = (w * 32 + seg * 16) * 32;
  }

  for (int k0 = 0; k0 < EMB; k0 += 32) {
    #pragma unroll
    for (int seg = 0; seg < 2; ++seg) {
      async16(sA[seg] + k0, &As[ldst[seg]]);
      async16(sW[seg] + k0, &Ws[ldst[seg]]);
    }
    __syncthreads();

    shortx8 af[4], wf[4];
    #pragma unroll
    for (int i = 0; i < 4; ++i) {
      af[i] = *(const shortx8*)&As[SWZ4(wm + i * 16 + lc, lq)];
      wf[i] = *(const shortx8*)&Ws[SWZ4(wn + i * 16 + lc, lq)];
    }
    #pragma unroll
    for (int i = 0; i < 4; ++i)
      #pragma unroll
      for (int jn = 0; jn < 4; ++jn)
        acc[i][jn] = __builtin_amdgcn_mfma_f32_16x16x32_bf16(af[i], wf[jn], acc[i][jn], 0, 0, 0);
    __syncthreads();
  }

  #pragma unroll
  for (int i = 0; i < 4; ++i) {
    int mrow0 = mt * 128 + wm + i * 16 + lq * 4;
    #pragma unroll
    for (int jn = 0; jn < 4; ++jn) {
      int col = col0 + wn + jn * 16 + lc;
      float bias = BP[col];
      #pragma unroll
      for (int r = 0; r < 4; ++r) {
        int mrow = mrow0 + r;
        float val = acc[i][jn][r] + bias + x[(size_t)mrow * EMB + col];
        out[((size_t)(modal * RPM + mrow)) * EMB + col] = val;
      }
    }
  }
}

extern "C" void kernel_launch(void* const* d_in, const int* in_sizes, int n_in,
                              void* d_out, int out_size, void* d_ws, size_t ws_size,
                              hipStream_t stream) {
  const float* modal1 = (const float*)d_in[0];
  const float* modal2 = (const float*)d_in[1];
  const float* ln1_g  = (const float*)d_in[2];
  const float* ln1_b  = (const float*)d_in[3];
  const float* w_qkv1 = (const float*)d_in[4];
  const float* b_qkv1 = (const float*)d_in[5];
  const float* w_proj1= (const float*)d_in[6];
  const float* b_proj1= (const float*)d_in[7];
  const float* ln2_g  = (const float*)d_in[8];
  const float* ln2_b  = (const float*)d_in[9];
  const float* w_qkv2 = (const float*)d_in[10];
  const float* b_qkv2 = (const float*)d_in[11];
  const float* w_proj2= (const float*)d_in[12];
  const float* b_proj2= (const float*)d_in[13];
  float* out = (float*)d_out;

  const size_t BUFE = (size_t)NROW * EMB;       // 6291456 elems
  const size_t WQE  = (size_t)2 * 2304 * EMB;   // 3538944 elems
  u16* xn_hi = (u16*)d_ws;
  u16* xn_lo = xn_hi + BUFE;
  u16* q_hi  = xn_lo + BUFE;
  u16* q_lo  = q_hi + BUFE;
  u16* k_hi  = q_lo + BUFE;
  u16* k_lo  = k_hi + BUFE;
  u16* vT    = k_lo + BUFE;
  u16* wq_h  = vT + BUFE;
  u16* wq_l  = wq_h + WQE;
  u16* attn  = xn_hi;   // xn dead after k_qkv
  u16* wp_h  = q_lo;    // q_lo dead after k_attn

  prep_wq<<<4608, 256, 0, stream>>>(w_qkv1, w_qkv2, wq_h, wq_l);
  k_ln<<<NROW, 256, 0, stream>>>(modal1, modal2, ln1_g, ln1_b, ln2_g, ln2_b, xn_hi, xn_lo);
  dim3 g2(32, 18, 2);
  k_qkv<<<g2, 256, 0, stream>>>(xn_hi, xn_lo, wq_h, wq_l, b_qkv1, b_qkv2,
                                q_hi, q_lo, k_hi, k_lo, vT);
  dim3 g3(48, 16);   // u fastest -> XCD = u%8 fixed across qt
  k_attn<<<g3, 256, 0, stream>>>(q_hi, q_lo, k_hi, k_lo, vT, attn);
  prep_wp<<<1536, 256, 0, stream>>>(w_proj1, w_proj2, wp_h);
  dim3 g4(32, 6, 2);
  k_proj<<<g4, 256, 0, stream>>>(attn, wp_h, modal1, modal2, b_proj1, b_proj2, out);
}